// Round 3
// baseline (236.464 us; speedup 1.0000x reference)
//
#include <hip/hip_runtime.h>

// out[b, c] = x[b, c] * diag[c]   for x:(8192, 4096) fp32, diag:(4096,) fp32.
// Memory-bound stream: grid-stride vec4 kernel, 2048 blocks (8/CU),
// diagonal load hoisted (stride is a multiple of SIZE4), nontemporal x/out.
// Native clang vector type (not HIP_vector_type) so nontemporal builtins accept it.

typedef float vfloat4 __attribute__((ext_vector_type(4)));

#define SIZE 4096
#define SIZE4 (SIZE / 4)            // 1024 vec4 groups per row (pow2)
#define N4 (8192 * SIZE / 4)        // 8,388,608 vec4 groups total

#define BLOCK 256
#define GRID 2048                   // 256 CUs x 8 blocks -> full residency
#define STRIDE (GRID * BLOCK)       // 524288 = 512 * 1024 -> multiple of SIZE4
#define ITERS (N4 / STRIDE)         // 16 exact

__global__ __launch_bounds__(BLOCK) void diag_scale_kernel(
    const vfloat4* __restrict__ x,
    const vfloat4* __restrict__ d,
    vfloat4* __restrict__ out)
{
    const int tid = blockIdx.x * BLOCK + threadIdx.x;

    // STRIDE % SIZE4 == 0, so the column (and thus the diagonal fragment)
    // is invariant across all ITERS iterations of this thread.
    const vfloat4 dv = d[tid & (SIZE4 - 1)];

    int i = tid;
#pragma unroll
    for (int it = 0; it < ITERS; ++it, i += STRIDE) {
        vfloat4 xv = __builtin_nontemporal_load(&x[i]);
        vfloat4 r = xv * dv;
        __builtin_nontemporal_store(r, &out[i]);
    }
}

extern "C" void kernel_launch(void* const* d_in, const int* in_sizes, int n_in,
                              void* d_out, int out_size, void* d_ws, size_t ws_size,
                              hipStream_t stream)
{
    const vfloat4* x = (const vfloat4*)d_in[0];   // (8192, 4096) fp32
    const vfloat4* d = (const vfloat4*)d_in[1];   // (4096,) fp32
    vfloat4* out = (vfloat4*)d_out;               // (8192, 4096) fp32

    diag_scale_kernel<<<GRID, BLOCK, 0, stream>>>(x, d, out);
}